// Round 9
// baseline (609.595 us; speedup 1.0000x reference)
//
#include <hip/hip_runtime.h>

// ============================================================================
// Decoder_70437463654609: 32-step LSTM recurrence, B=2048 H=512 HID=16.
// R17 = R12 (proven-passing 477us skeleton: wid==0 poll + loop-head barrier,
// agent-scope flags/stores, system-scope A-loads, counted vmcnt DEPTH-8)
//  + breg0 hoist ONLY (the sync-free half of R15):
//    b0 B-fragments for c<16 are loop-invariant across all 32 steps ->
//    hoisted to 64 VGPRs; removes 25% of per-step GEMM ds_read_b128 + addr
//    VALU. Worst failure mode = VGPR spill (visible dur regression), never
//    a hang. Bisects R15/R16's container-killer: if this passes, chunked
//    polling was the killer; if it fails, breg0/infra is implicated.
// Graph = memset(flags) + persist only.
// ============================================================================

#define TSEQ  32
#define BATCH 2048
#define HDIM  512
#define NBLK  256
#define NTHR  512
#define DEPTH 8

typedef __bf16 bf16x8 __attribute__((ext_vector_type(8)));
typedef float  f32x16 __attribute__((ext_vector_type(16)));
typedef unsigned u32x4 __attribute__((ext_vector_type(4)));
typedef unsigned long long u64;

// ---- LDS layout (byte offsets), total 163,360 <= 163,840 ----
#define BS_OFF     0          // Bs: w_hh [128 n][64 k8 x 16B] swz (131072); init: B-atoms(32KB)+W1T+bT
#define HPW_OFF    131072     // hp_w1 atoms [16 n][64 k8 x 16B] swz (16384)
#define UNI_OFF    147456     // union: h2s [128][20] f32 (10240) | hP bf16 [128][36] (9216)
#define H1_OFF     157696     // h1s [128 m][16 bf16] stride 32 B (4096)
#define LPS_OFF    161792     // lps [128][2] f32 (1024)
#define PRM_OFF    162816     // folded params (130 f32) (544)
#define LDS_TOTAL  163360
// init-phase temporaries inside the Bs region:
#define W1T_OFF    32768      // [128][17] f32 (8704)
#define BT_OFF     41472      // [128] f32 (512)

// ---- workspace layout (bytes) ----
#define WS_FLAGS  0                        // 16 groups x 128 B (memset to 0)
#define WS_HATOM  2048                     // 2 x (16 mt x 128 KB) h atoms

__device__ __forceinline__ unsigned f2bf(float f) {   // RNE f32->bf16 (low 16)
  unsigned u = __float_as_uint(f);
  u += 0x7fffu + ((u >> 16) & 1u);
  return u >> 16;
}
// relaxed agent-scope ops (device-coherent via MALL) — R12-proven
__device__ __forceinline__ void st8(void* p, u64 v) {
  __hip_atomic_store((u64*)p, v, __ATOMIC_RELAXED, __HIP_MEMORY_SCOPE_AGENT);
}
__device__ __forceinline__ unsigned ld4(const unsigned* p) {
  return __hip_atomic_load(p, __ATOMIC_RELAXED, __HIP_MEMORY_SCOPE_AGENT);
}
__device__ __forceinline__ void st4(unsigned* p, unsigned v) {
  __hip_atomic_store(p, v, __ATOMIC_RELAXED, __HIP_MEMORY_SCOPE_AGENT);
}
// system-scope bulk load for the h-atom exchange; result NOT ready until an
// explicit s_waitcnt vmcnt — compiler does not track it.
__device__ __forceinline__ u32x4 ld16_dev(const void* p) {
  u32x4 r;
  asm volatile("global_load_dwordx4 %0, %1, off sc0 sc1"
               : "=&v"(r) : "v"(p) : "memory");
  return r;
}
__device__ __forceinline__ void vm_drain() {
  asm volatile("s_waitcnt vmcnt(0)" ::: "memory");
}
// counted vmem wait + hard scheduling fence (rule #18: keep MFMA below it)
#define WAITV(n) do { asm volatile("s_waitcnt vmcnt(" #n ")" ::: "memory"); \
                      __builtin_amdgcn_sched_barrier(0); } while (0)

// quad-perm broadcasts / swaps
#define QB(x, imm) __uint_as_float((unsigned)__builtin_amdgcn_mov_dpp((int)__float_as_uint(x), imm, 0xF, 0xF, true))

struct KParams {
  const float *last_pos, *hh, *ch0, *w_hh, *w_ih, *b_ih, *b_hh;
  const float *se_w1, *se_b1, *se_g, *se_bt, *se_m, *se_v, *se_w2, *se_b2;
  const float *hp_w1, *hp_b1, *hp_g, *hp_bt, *hp_m, *hp_v, *hp_w2, *hp_b2;
  char* hatom;            // 2 parities x 2 MB
  unsigned* flags;        // 16 groups x 32 u32
  float* out;
};

// ---------------------------------------------------------------------------
// Persistent kernel. 256 blocks x 512 threads, 1 block/CU (plain launch).
// Block (mt, nt): rows [mt*128,+128), local n = 4*jj + gate.
// ---------------------------------------------------------------------------
__global__ __launch_bounds__(NTHR, 2) void decoder_persist(KParams p) {
  extern __shared__ char lds[];
  const int tid  = threadIdx.x;
  const int lane = tid & 63;
  const int wid  = tid >> 6;
  const int wm   = wid >> 1;
  const int wn   = wid & 1;
  const int mt   = blockIdx.x >> 4;
  const int nt   = blockIdx.x & 15;
  const int m0   = mt * 128;

  float* prm = (float*)(lds + PRM_OFF);
  float* lps = (float*)(lds + LPS_OFF);
  float* h2s = (float*)(lds + UNI_OFF);                    // stride 20 f32
  unsigned short* hPsh = (unsigned short*)(lds + UNI_OFF); // stride 36 u16
  float* W1T = (float*)(lds + W1T_OFF);                    // [128][17]
  float* bT  = (float*)(lds + BT_OFF);                     // [128]

  const int n0 = wn * 64 + (lane & 31);
  const int n1 = n0 + 32;
  const int gate = lane & 3;
  const int khalf = lane >> 5;
  const int pj = ((tid >> 8) << 1) | ((tid >> 5) & 1);
  const int pm = ((tid >> 6) & 3) * 32 + (tid & 31);

  // ================= one-time init =================
  if (tid < 16) {
    int q = tid;
    float sA = p.se_g[q] * rsqrtf(p.se_v[q] + 1e-5f);
    prm[q]      = sA;
    prm[16 + q] = (p.se_b1[q] - p.se_m[q]) * sA + p.se_bt[q];
    float hA = p.hp_g[q] * rsqrtf(p.hp_v[q] + 1e-5f);
    prm[32 + q] = hA;
    prm[48 + q] = (p.hp_b1[q] - p.hp_m[q]) * hA + p.hp_bt[q];
  }
  if (tid < 32) { prm[64 + tid] = p.se_w1[tid]; prm[96 + tid] = p.hp_w2[tid]; }
  if (tid < 2)  { prm[128 + tid] = p.hp_b2[tid]; }
  if (tid < 256) lps[tid] = p.last_pos[(size_t)m0 * 2 + tid];

  // ---- stage init B-atoms: cols 0..15 = se_w2 rows, 16 = se_b2, 17..31 = 0
  for (int a = tid; a < 2048; a += NTHR) {
    int n = a >> 6, k8 = a & 63;
    uint4 v = {0, 0, 0, 0};
    if (n <= 16) {
      const float* src = (n < 16) ? (p.se_w2 + (size_t)n * 512 + k8 * 8)
                                  : (p.se_b2 + k8 * 8);
      v.x = f2bf(src[0]) | (f2bf(src[1]) << 16);
      v.y = f2bf(src[2]) | (f2bf(src[3]) << 16);
      v.z = f2bf(src[4]) | (f2bf(src[5]) << 16);
      v.w = f2bf(src[6]) | (f2bf(src[7]) << 16);
    }
    *(uint4*)(lds + BS_OFF + ((size_t)(n * 64 + (k8 ^ (n & 7)))) * 16) = v;
  }
  __syncthreads();

  // ---- init-MFMA: W1f[128 gate-rows][16] = w_ih_slice @ se_w2^T (+bias col 16)
  if ((wid & 1) == 0) {
    int rloc = wm * 32 + (lane & 31);
    int grow = (rloc & 3) * 512 + nt * 32 + (rloc >> 2);
    const float* arow = p.w_ih + (size_t)grow * 512;
    f32x16 accW;
    #pragma unroll
    for (int i = 0; i < 16; ++i) accW[i] = 0.f;
    float4 pa[4], pb[4];
    #pragma unroll
    for (int j = 0; j < 4; ++j) {
      int kal = j * 2 + khalf;
      pa[j] = ((const float4*)(arow + kal * 8))[0];
      pb[j] = ((const float4*)(arow + kal * 8))[1];
    }
    #pragma unroll
    for (int c = 0; c < 32; ++c) {
      int kal = c * 2 + khalf;
      union { unsigned short s[8]; bf16x8 v; } av;
      float4 a = pa[c & 3], b = pb[c & 3];
      av.s[0] = f2bf(a.x); av.s[1] = f2bf(a.y); av.s[2] = f2bf(a.z); av.s[3] = f2bf(a.w);
      av.s[4] = f2bf(b.x); av.s[5] = f2bf(b.y); av.s[6] = f2bf(b.z); av.s[7] = f2bf(b.w);
      if (c + 4 < 32) {
        int kn = (c + 4) * 2 + khalf;
        pa[c & 3] = ((const float4*)(arow + kn * 8))[0];
        pb[c & 3] = ((const float4*)(arow + kn * 8))[1];
      }
      int q = lane & 31;
      bf16x8 bp = *(const bf16x8*)(lds + BS_OFF + (((q << 6) + (kal ^ (q & 7))) << 4));
      accW = __builtin_amdgcn_mfma_f32_32x32x16_bf16(av.v, bp, accW, 0, 0, 0);
    }
    int q = lane & 31;
    #pragma unroll
    for (int r = 0; r < 16; ++r) {
      int row = (r & 3) + 8 * (r >> 2) + 4 * khalf + wm * 32;
      if (q < 16) {
        W1T[row * 17 + q] = accW[r];
      } else if (q == 16) {
        int g2 = (row & 3) * 512 + nt * 32 + (row >> 2);
        bT[row] = accW[r] + p.b_ih[g2] + p.b_hh[g2];
      }
    }
  }
  __syncthreads();

  // ---- read xg fragments + bias from LDS temps; convert h0 atoms
  union BW { unsigned short s[8]; bf16x8 v; } w0f, w1f;
  #pragma unroll
  for (int j = 0; j < 8; ++j) {
    w0f.s[j] = (unsigned short)f2bf(W1T[n0 * 17 + khalf * 8 + j]);
    w1f.s[j] = (unsigned short)f2bf(W1T[n1 * 17 + khalf * 8 + j]);
  }
  float biasr[2];
  biasr[0] = bT[wn * 64 + (lane & 31)];
  biasr[1] = bT[wn * 64 + 32 + (lane & 31)];
  {
    // h0 -> parity-1 atoms, exactly this block's store region
    const float* src = p.hh + (size_t)(m0 + pm) * 512 + nt * 32 + pj * 8;
    float4 f0 = ((const float4*)src)[0];
    float4 f1 = ((const float4*)src)[1];
    u64 lo = (u64)f2bf(f0.x) | ((u64)f2bf(f0.y) << 16)
           | ((u64)f2bf(f0.z) << 32) | ((u64)f2bf(f0.w) << 48);
    u64 hi = (u64)f2bf(f1.x) | ((u64)f2bf(f1.y) << 16)
           | ((u64)f2bf(f1.z) << 32) | ((u64)f2bf(f1.w) << 48);
    u64* hdst = (u64*)(p.hatom + 2097152 + mt * 131072);
    st8(hdst + (512 * nt + tid) * 2,     lo);
    st8(hdst + (512 * nt + tid) * 2 + 1, hi);
  }
  __syncthreads();                      // drains h0 st8 (vmcnt before barrier)
  if (tid == 0) st4(p.flags + mt * 32 + nt, 1u);

  // ---- Bs: w_hh slice -> bf16 atoms (overwrite init temps)
  for (int a = tid; a < 8192; a += NTHR) {
    int n = a >> 6, ka = a & 63;
    int grow = (n & 3) * 512 + nt * 32 + (n >> 2);
    const float* src = p.w_hh + (size_t)grow * 512 + ka * 8;
    uint4 v;
    v.x = f2bf(src[0]) | (f2bf(src[1]) << 16);
    v.y = f2bf(src[2]) | (f2bf(src[3]) << 16);
    v.z = f2bf(src[4]) | (f2bf(src[5]) << 16);
    v.w = f2bf(src[6]) | (f2bf(src[7]) << 16);
    *(uint4*)(lds + BS_OFF + ((size_t)(n * 64 + (ka ^ (n & 7)))) * 16) = v;
  }
  // hp_w1 atoms: atom (n<16, k8) = hp_w1[k8*8+j][n]
  for (int a = tid; a < 1024; a += NTHR) {
    int n = a >> 6, k8 = a & 63;
    const float* src = p.hp_w1 + (size_t)(k8 * 8) * 16 + n;
    uint4 v;
    v.x = f2bf(src[0])  | (f2bf(src[16]) << 16);
    v.y = f2bf(src[32]) | (f2bf(src[48]) << 16);
    v.z = f2bf(src[64]) | (f2bf(src[80]) << 16);
    v.w = f2bf(src[96]) | (f2bf(src[112]) << 16);
    *(uint4*)(lds + HPW_OFF + ((size_t)(n * 64 + (k8 ^ (n & 7)))) * 16) = v;
  }
  // c state (lanes with lane%4==0)
  float c_st[2][16];
  #pragma unroll
  for (int t2 = 0; t2 < 2; ++t2)
    #pragma unroll
    for (int r = 0; r < 16; ++r) c_st[t2][r] = 0.f;
  if ((lane & 3) == 0) {
    #pragma unroll
    for (int t2 = 0; t2 < 2; ++t2) {
      int jj = (wn * 64 + t2 * 32 + (lane & 31)) >> 2;
      #pragma unroll
      for (int r = 0; r < 16; ++r) {
        int row = (r & 3) + 8 * (r >> 2) + 4 * khalf + wm * 32;
        c_st[t2][r] = p.ch0[(size_t)(m0 + row) * 512 + nt * 32 + jj];
      }
    }
  }
  __syncthreads();

  // ---- hoist b0 fragments for c<16 into registers (loop-invariant) ----
  bf16x8 breg0[16];
  #pragma unroll
  for (int cc = 0; cc < 16; ++cc) {
    int kk = cc * 2 + khalf;
    breg0[cc] = *(const bf16x8*)(lds + BS_OFF + (((n0 << 6) + (kk ^ (n0 & 7))) << 4));
  }

  float sA2q = 0.f, bA2q = 0.f;
  if ((lane & 31) < 16) { sA2q = prm[32 + (lane & 31)]; bA2q = prm[48 + (lane & 31)]; }
  const unsigned* fl = p.flags + mt * 32 + (lane & 15);

  // ================= main loop =================
  for (int t = 0; t < TSEQ; ++t) {
    if (wid == 0) {
      while (!__all((int)(ld4(fl) >= (unsigned)(t + 1))))
        __builtin_amdgcn_s_sleep(2);
    }
    __syncthreads();

    // ---------- GEMM over h_t: gates (acc0,acc1) + P (accP, wn==0) ----------
    f32x16 acc0, acc1, accP;
    #pragma unroll
    for (int i = 0; i < 16; ++i) { acc0[i] = 0.f; acc1[i] = 0.f; accP[i] = 0.f; }
    {
      const char* abase = p.hatom + (size_t)((t + 1) & 1) * 2097152 + mt * 131072
                          + (wm * 64 + lane) * 16;
      vm_drain();                               // clean vmcnt baseline
      u32x4 pre[DEPTH];
      #pragma unroll
      for (int c = 0; c < DEPTH; ++c) pre[c] = ld16_dev(abase + c * 4096);
      union AB { u32x4 u; bf16x8 v; };
      #pragma unroll
      for (int c = 0; c < 32; ++c) {
        switch (c) {
          default: WAITV(7); break;
          case 25: WAITV(6); break;
          case 26: WAITV(5); break;
          case 27: WAITV(4); break;
          case 28: WAITV(3); break;
          case 29: WAITV(2); break;
          case 30: WAITV(1); break;
          case 31: WAITV(0); break;
        }
        AB u;
        u.u = pre[c & (DEPTH - 1)];
        if (c + DEPTH < 32)
          pre[c & (DEPTH - 1)] = ld16_dev(abase + (c + DEPTH) * 4096);
        int kal = c * 2 + khalf;
        bf16x8 b0 = (c < 16) ? breg0[c]
          : *(const bf16x8*)(lds + BS_OFF + (((n0 << 6) + (kal ^ (n0 & 7))) << 4));
        bf16x8 b1 = *(const bf16x8*)(lds + BS_OFF + (((n1 << 6) + (kal ^ (n1 & 7))) << 4));
        acc0 = __builtin_amdgcn_mfma_f32_32x32x16_bf16(u.v, b0, acc0, 0, 0, 0);
        acc1 = __builtin_amdgcn_mfma_f32_32x32x16_bf16(u.v, b1, acc1, 0, 0, 0);
        if (wn == 0) {
          bf16x8 bp = {};
          if ((lane & 31) < 16)
            bp = *(const bf16x8*)(lds + HPW_OFF
                  + ((((lane & 31) << 6) + (kal ^ (lane & 7))) << 4));
          accP = __builtin_amdgcn_mfma_f32_32x32x16_bf16(u.v, bp, accP, 0, 0, 0);
        }
      }
    }

    // ---------- P -> h2s (wn==0 waves) ----------
    if (t > 0) {
      if (wn == 0 && (lane & 31) < 16) {
        int q = lane & 31;
        #pragma unroll
        for (int r = 0; r < 16; ++r) {
          int row = (r & 3) + 8 * (r >> 2) + 4 * khalf + wm * 32;
          h2s[row * 20 + q] = fmaxf(accP[r] * sA2q + bA2q, 0.f);
        }
      }
      __syncthreads();
    }

    // ---------- merged lp + h1 (threads < 256; DPP pair swap) ----------
    if (tid < 256) {
      int m = tid >> 1, c = tid & 1;
      float lp0, lp1;
      if (t > 0) {
        float a2 = prm[128 + c];
        const float4* hrow = (const float4*)(lds + UNI_OFF + m * 80);
        #pragma unroll
        for (int g4 = 0; g4 < 4; ++g4) {
          float4 v = hrow[g4];
          a2 += v.x * prm[96 + (g4 * 4 + 0) * 2 + c];
          a2 += v.y * prm[96 + (g4 * 4 + 1) * 2 + c];
          a2 += v.z * prm[96 + (g4 * 4 + 2) * 2 + c];
          a2 += v.w * prm[96 + (g4 * 4 + 3) * 2 + c];
        }
        float lpv = 1.f / (1.f + __expf(-(a2 + lps[tid])));
        lps[tid] = lpv;
        if (nt == 0)
          p.out[((size_t)(t - 1) * BATCH + m0 + m) * 2 + c] = lpv;
        float other = QB(lpv, 0xB1);                   // swap within lane pair
        lp0 = c ? other : lpv;
        lp1 = c ? lpv : other;
      } else {
        lp0 = lps[m * 2];
        lp1 = lps[m * 2 + 1];
      }
      // h1 for q = c*8 .. c*8+7, packed 16 B store
      u64 hq[2];
      #pragma unroll
      for (int half = 0; half < 2; ++half) {
        u64 w = 0;
        #pragma unroll
        for (int i = 0; i < 4; ++i) {
          int q = c * 8 + half * 4 + i;
          float z = lp0 * prm[64 + q] + lp1 * prm[80 + q];
          w |= (u64)f2bf(fmaxf(z * prm[q] + prm[16 + q], 0.f)) << (16 * i);
        }
        hq[half] = w;
      }
      u64* hd = (u64*)(lds + H1_OFF + m * 32 + c * 16);
      hd[0] = hq[0];
      hd[1] = hq[1];
    }
    __syncthreads();

    // ---------- xg contribution (last MFMA) ----------
    {
      bf16x8 a1 = *(const bf16x8*)(lds + H1_OFF + (wm * 32 + (lane & 31)) * 32 + khalf * 16);
      acc0 = __builtin_amdgcn_mfma_f32_32x32x16_bf16(a1, w0f.v, acc0, 0, 0, 0);
      acc1 = __builtin_amdgcn_mfma_f32_32x32x16_bf16(a1, w1f.v, acc1, 0, 0, 0);
    }

    // ---------- epilogue: LSTM cell update ----------
    #pragma unroll
    for (int t2 = 0; t2 < 2; ++t2) {
      float bias = biasr[t2];
      int jj = (wn * 64 + t2 * 32 + (lane & 31)) >> 2;
      float act[16];
      const f32x16& A = (t2 == 0) ? acc0 : acc1;
      #pragma unroll
      for (int r = 0; r < 16; ++r) {
        float v = A[r] + bias;
        float vv = (gate == 2) ? 2.f * v : v;
        float sg = 1.f / (1.f + __expf(-vv));
        act[r] = (gate == 2) ? 2.f * sg - 1.f : sg;
      }
      #pragma unroll
      for (int r = 0; r < 16; ++r) {
        float iv = QB(act[r], 0x00);
        float fv = QB(act[r], 0x55);
        float gv = QB(act[r], 0xAA);
        float ov = QB(act[r], 0xFF);
        float cn = fv * c_st[t2][r] + iv * gv;
        c_st[t2][r] = cn;
        float th = 2.f / (1.f + __expf(-2.f * cn)) - 1.f;
        float hn = ov * th;
        if ((lane & 3) == 0) {
          int row = (r & 3) + 8 * (r >> 2) + 4 * khalf + wm * 32;
          hPsh[row * 36 + jj] = (unsigned short)f2bf(hn);
        }
      }
    }
    __syncthreads();

    // ---------- coalesced h-atom stores (sc0sc1 write-through) + flag ----------
    {
      const u64* hp8 = (const u64*)(lds + UNI_OFF + pm * 72 + pj * 16);
      u64* hdst = (u64*)(p.hatom + (size_t)(t & 1) * 2097152 + mt * 131072);
      st8(hdst + (512 * nt + tid) * 2,     hp8[0]);
      st8(hdst + (512 * nt + tid) * 2 + 1, hp8[1]);
    }
    __syncthreads();   // implicit vmcnt(0) drains the sc1 stores
    if (tid == 0) st4(p.flags + mt * 32 + nt, (unsigned)(t + 2));
  }

  // ---------- tail (t=32): P(h_32) only -> lp_32 -> out[31] ----------
  {
    if (wid == 0) {
      while (!__all((int)(ld4(fl) >= (unsigned)(TSEQ + 1))))
        __builtin_amdgcn_s_sleep(2);
    }
    __syncthreads();
    f32x16 accP;
    #pragma unroll
    for (int i = 0; i < 16; ++i) accP[i] = 0.f;
    if (wn == 0) {
      const char* abase = p.hatom + 2097152 + mt * 131072 + (wm * 64 + lane) * 16;
      vm_drain();
      u32x4 pre[DEPTH];
      #pragma unroll
      for (int c = 0; c < DEPTH; ++c) pre[c] = ld16_dev(abase + c * 4096);
      union AB { u32x4 u; bf16x8 v; };
      #pragma unroll
      for (int c = 0; c < 32; ++c) {
        switch (c) {
          default: WAITV(7); break;
          case 25: WAITV(6); break;
          case 26: WAITV(5); break;
          case 27: WAITV(4); break;
          case 28: WAITV(3); break;
          case 29: WAITV(2); break;
          case 30: WAITV(1); break;
          case 31: WAITV(0); break;
        }
        AB u;
        u.u = pre[c & (DEPTH - 1)];
        if (c + DEPTH < 32)
          pre[c & (DEPTH - 1)] = ld16_dev(abase + (c + DEPTH) * 4096);
        int kal = c * 2 + khalf;
        bf16x8 bp = {};
        if ((lane & 31) < 16)
          bp = *(const bf16x8*)(lds + HPW_OFF
                + ((((lane & 31) << 6) + (kal ^ (lane & 7))) << 4));
        accP = __builtin_amdgcn_mfma_f32_32x32x16_bf16(u.v, bp, accP, 0, 0, 0);
      }
      if ((lane & 31) < 16) {
        int q = lane & 31;
        #pragma unroll
        for (int r = 0; r < 16; ++r) {
          int row = (r & 3) + 8 * (r >> 2) + 4 * khalf + wm * 32;
          h2s[row * 20 + q] = fmaxf(accP[r] * sA2q + bA2q, 0.f);
        }
      }
    }
    __syncthreads();
    if (tid < 256 && nt == 0) {
      int m = tid >> 1, c = tid & 1;
      float a2 = prm[128 + c];
      const float4* hrow = (const float4*)(lds + UNI_OFF + m * 80);
      #pragma unroll
      for (int g4 = 0; g4 < 4; ++g4) {
        float4 v = hrow[g4];
        a2 += v.x * prm[96 + (g4 * 4 + 0) * 2 + c];
        a2 += v.y * prm[96 + (g4 * 4 + 1) * 2 + c];
        a2 += v.z * prm[96 + (g4 * 4 + 2) * 2 + c];
        a2 += v.w * prm[96 + (g4 * 4 + 3) * 2 + c];
      }
      float lpv = 1.f / (1.f + __expf(-(a2 + lps[tid])));
      p.out[((size_t)(TSEQ - 1) * BATCH + m0 + m) * 2 + c] = lpv;
    }
  }
}

// ---------------------------------------------------------------------------
extern "C" void kernel_launch(void* const* d_in, const int* in_sizes, int n_in,
                              void* d_out, int out_size, void* d_ws, size_t ws_size,
                              hipStream_t stream) {
  char* ws = (char*)d_ws;
  KParams kp;
  kp.last_pos = (const float*)d_in[0];
  kp.hh    = (const float*)d_in[1];
  kp.ch0   = (const float*)d_in[2];
  kp.se_w1 = (const float*)d_in[3];
  kp.se_b1 = (const float*)d_in[4];
  kp.se_g  = (const float*)d_in[5];
  kp.se_bt = (const float*)d_in[6];
  kp.se_m  = (const float*)d_in[7];
  kp.se_v  = (const float*)d_in[8];
  kp.se_w2 = (const float*)d_in[9];
  kp.se_b2 = (const float*)d_in[10];
  kp.w_ih  = (const float*)d_in[11];
  kp.w_hh  = (const float*)d_in[12];
  kp.b_ih  = (const float*)d_in[13];
  kp.b_hh  = (const float*)d_in[14];
  kp.hp_w1 = (const float*)d_in[15];
  kp.hp_b1 = (const float*)d_in[16];
  kp.hp_g  = (const float*)d_in[17];
  kp.hp_bt = (const float*)d_in[18];
  kp.hp_m  = (const float*)d_in[19];
  kp.hp_v  = (const float*)d_in[20];
  kp.hp_w2 = (const float*)d_in[21];
  kp.hp_b2 = (const float*)d_in[22];
  kp.flags = (unsigned*)(ws + WS_FLAGS);
  kp.hatom = ws + WS_HATOM;
  kp.out   = (float*)d_out;

  (void)hipMemsetAsync(ws + WS_FLAGS, 0, 2048, stream);
  (void)hipFuncSetAttribute((const void*)decoder_persist,
                            hipFuncAttributeMaxDynamicSharedMemorySize, LDS_TOTAL);
  decoder_persist<<<dim3(NBLK), dim3(NTHR), LDS_TOTAL, stream>>>(kp);
}

// Round 10
// 578.253 us; speedup vs baseline: 1.0542x; 1.0542x over previous
//
#include <hip/hip_runtime.h>

// ============================================================================
// Decoder_70437463654609: 32-step LSTM recurrence, B=2048 H=512 HID=16.
// R18 = R12 (proven 477us) + INCREMENTAL REGION GATING, breg0 reverted
// (R17 post-mortem: VGPR 128 cap + scratch spill, WRITE_SIZE +9MB):
//  * GEMM consumes producer regions in c-order (region = c/2). Iteration c
//    is gated on ready-prefix >= min(16, (c+8)/2+1) (prefetch lookahead
//    included) -> consumer compute overlaps producer straggler spread.
//  * ONE wave (wid0) polls the 16 flags at MALL (single-wave poll =
//    R12-proven; R15/16's 8-wave MALL hammer suspected container-killer)
//    and publishes a monotone token (t*16+prefix) in LDS; other waves spin
//    on the CU-local token. Deadlock-free: wid0's polls terminate (monotone
//    flags, producers independent), it always publishes, req reaches 16 by
//    c=22 so WAR protection on parity buffers is preserved exactly as R12.
//  * wid0 poll loads are asm with vmcnt(0) drain -> counted WAITV window
//    can never be miscounted (drain only costs when actually stalled).
// Graph = memset(flags) + persist only.
// ============================================================================

#define TSEQ  32
#define BATCH 2048
#define HDIM  512
#define NBLK  256
#define NTHR  512
#define DEPTH 8

typedef __bf16 bf16x8 __attribute__((ext_vector_type(8)));
typedef float  f32x16 __attribute__((ext_vector_type(16)));
typedef unsigned u32x4 __attribute__((ext_vector_type(4)));
typedef unsigned long long u64;

// ---- LDS layout (byte offsets), total 163,368 <= 163,840 ----
#define BS_OFF     0          // Bs: w_hh [128 n][64 k8 x 16B] swz (131072); init: B-atoms(32KB)+W1T+bT
#define HPW_OFF    131072     // hp_w1 atoms [16 n][64 k8 x 16B] swz (16384)
#define UNI_OFF    147456     // union: h2s [128][20] f32 (10240) | hP bf16 [128][36] (9216)
#define H1_OFF     157696     // h1s [128 m][16 bf16] stride 32 B (4096)
#define LPS_OFF    161792     // lps [128][2] f32 (1024)
#define PRM_OFF    162816     // folded params (130 f32) (544)
#define TOK_OFF    163360     // ready-prefix token (1 int, monotone)
#define LDS_TOTAL  163368
// init-phase temporaries inside the Bs region:
#define W1T_OFF    32768      // [128][17] f32 (8704)
#define BT_OFF     41472      // [128] f32 (512)

// ---- workspace layout (bytes) ----
#define WS_FLAGS  0                        // 16 groups x 128 B (memset to 0)
#define WS_HATOM  2048                     // 2 x (16 mt x 128 KB) h atoms

__device__ __forceinline__ unsigned f2bf(float f) {   // RNE f32->bf16 (low 16)
  unsigned u = __float_as_uint(f);
  u += 0x7fffu + ((u >> 16) & 1u);
  return u >> 16;
}
// relaxed agent-scope ops (device-coherent via MALL) — R12-proven
__device__ __forceinline__ void st8(void* p, u64 v) {
  __hip_atomic_store((u64*)p, v, __ATOMIC_RELAXED, __HIP_MEMORY_SCOPE_AGENT);
}
__device__ __forceinline__ void st4(unsigned* p, unsigned v) {
  __hip_atomic_store(p, v, __ATOMIC_RELAXED, __HIP_MEMORY_SCOPE_AGENT);
}
// system-scope bulk load for the h-atom exchange; result NOT ready until an
// explicit s_waitcnt vmcnt — compiler does not track it.
__device__ __forceinline__ u32x4 ld16_dev(const void* p) {
  u32x4 r;
  asm volatile("global_load_dwordx4 %0, %1, off sc0 sc1"
               : "=&v"(r) : "v"(p) : "memory");
  return r;
}
// poll load: device-scope + full drain (safe inside the counted window;
// only costs when we are actually stalled waiting for stragglers).
__device__ __forceinline__ unsigned ld4_drain(const unsigned* p) {
  unsigned r;
  asm volatile("global_load_dword %0, %1, off sc0 sc1\n\ts_waitcnt vmcnt(0)"
               : "=v"(r) : "v"(p) : "memory");
  return r;
}
__device__ __forceinline__ void vm_drain() {
  asm volatile("s_waitcnt vmcnt(0)" ::: "memory");
}
// counted vmem wait + hard scheduling fence (rule #18: keep MFMA below it)
#define WAITV(n) do { asm volatile("s_waitcnt vmcnt(" #n ")" ::: "memory"); \
                      __builtin_amdgcn_sched_barrier(0); } while (0)

// quad-perm broadcasts / swaps
#define QB(x, imm) __uint_as_float((unsigned)__builtin_amdgcn_mov_dpp((int)__float_as_uint(x), imm, 0xF, 0xF, true))

// region-readiness gate: wid0 polls MALL flags, publishes prefix token in
// LDS; other waves spin on the CU-local token. REQ is compile-time.
#define GATE(REQ, TT)                                                          \
  do {                                                                         \
    if (wid == 0) {                                                            \
      while (pfx < (REQ)) {                                                    \
        unsigned fv = ld4_drain(flp);                                          \
        unsigned m16 = (unsigned)__ballot((int)(fv >= (unsigned)((TT) + 1)))   \
                       & 0xFFFFu;                                              \
        pfx = (int)__builtin_ctz(~m16 | 0x10000u);                             \
        if (lane == 0) *tok = (TT) * 16 + pfx;                                 \
        if (pfx < (REQ)) __builtin_amdgcn_s_sleep(1);                          \
      }                                                                        \
    } else {                                                                   \
      if (tokr < (TT) * 16 + (REQ)) {                                          \
        while ((tokr = *tok) < (TT) * 16 + (REQ))                              \
          __builtin_amdgcn_s_sleep(1);                                         \
      }                                                                        \
    }                                                                          \
    __builtin_amdgcn_sched_barrier(0);                                         \
  } while (0)

#define REQC(c) ((((c) + DEPTH) >> 1) + 1 > 16 ? 16 : (((c) + DEPTH) >> 1) + 1)

struct KParams {
  const float *last_pos, *hh, *ch0, *w_hh, *w_ih, *b_ih, *b_hh;
  const float *se_w1, *se_b1, *se_g, *se_bt, *se_m, *se_v, *se_w2, *se_b2;
  const float *hp_w1, *hp_b1, *hp_g, *hp_bt, *hp_m, *hp_v, *hp_w2, *hp_b2;
  char* hatom;            // 2 parities x 2 MB
  unsigned* flags;        // 16 groups x 32 u32
  float* out;
};

// ---------------------------------------------------------------------------
// Persistent kernel. 256 blocks x 512 threads, 1 block/CU (plain launch).
// Block (mt, nt): rows [mt*128,+128), local n = 4*jj + gate.
// ---------------------------------------------------------------------------
__global__ __launch_bounds__(NTHR, 2) void decoder_persist(KParams p) {
  extern __shared__ char lds[];
  const int tid  = threadIdx.x;
  const int lane = tid & 63;
  const int wid  = tid >> 6;
  const int wm   = wid >> 1;
  const int wn   = wid & 1;
  const int mt   = blockIdx.x >> 4;
  const int nt   = blockIdx.x & 15;
  const int m0   = mt * 128;

  float* prm = (float*)(lds + PRM_OFF);
  float* lps = (float*)(lds + LPS_OFF);
  float* h2s = (float*)(lds + UNI_OFF);                    // stride 20 f32
  unsigned short* hPsh = (unsigned short*)(lds + UNI_OFF); // stride 36 u16
  float* W1T = (float*)(lds + W1T_OFF);                    // [128][17]
  float* bT  = (float*)(lds + BT_OFF);                     // [128]
  volatile int* tok = (volatile int*)(lds + TOK_OFF);

  const int n0 = wn * 64 + (lane & 31);
  const int n1 = n0 + 32;
  const int gate = lane & 3;
  const int khalf = lane >> 5;
  const int pj = ((tid >> 8) << 1) | ((tid >> 5) & 1);
  const int pm = ((tid >> 6) & 3) * 32 + (tid & 31);

  // ================= one-time init =================
  if (tid < 16) {
    int q = tid;
    float sA = p.se_g[q] * rsqrtf(p.se_v[q] + 1e-5f);
    prm[q]      = sA;
    prm[16 + q] = (p.se_b1[q] - p.se_m[q]) * sA + p.se_bt[q];
    float hA = p.hp_g[q] * rsqrtf(p.hp_v[q] + 1e-5f);
    prm[32 + q] = hA;
    prm[48 + q] = (p.hp_b1[q] - p.hp_m[q]) * hA + p.hp_bt[q];
  }
  if (tid < 32) { prm[64 + tid] = p.se_w1[tid]; prm[96 + tid] = p.hp_w2[tid]; }
  if (tid < 2)  { prm[128 + tid] = p.hp_b2[tid]; }
  if (tid < 256) lps[tid] = p.last_pos[(size_t)m0 * 2 + tid];
  if (tid == 0) *tok = 0;

  // ---- stage init B-atoms: cols 0..15 = se_w2 rows, 16 = se_b2, 17..31 = 0
  for (int a = tid; a < 2048; a += NTHR) {
    int n = a >> 6, k8 = a & 63;
    uint4 v = {0, 0, 0, 0};
    if (n <= 16) {
      const float* src = (n < 16) ? (p.se_w2 + (size_t)n * 512 + k8 * 8)
                                  : (p.se_b2 + k8 * 8);
      v.x = f2bf(src[0]) | (f2bf(src[1]) << 16);
      v.y = f2bf(src[2]) | (f2bf(src[3]) << 16);
      v.z = f2bf(src[4]) | (f2bf(src[5]) << 16);
      v.w = f2bf(src[6]) | (f2bf(src[7]) << 16);
    }
    *(uint4*)(lds + BS_OFF + ((size_t)(n * 64 + (k8 ^ (n & 7)))) * 16) = v;
  }
  __syncthreads();

  // ---- init-MFMA: W1f[128 gate-rows][16] = w_ih_slice @ se_w2^T (+bias col 16)
  if ((wid & 1) == 0) {
    int rloc = wm * 32 + (lane & 31);
    int grow = (rloc & 3) * 512 + nt * 32 + (rloc >> 2);
    const float* arow = p.w_ih + (size_t)grow * 512;
    f32x16 accW;
    #pragma unroll
    for (int i = 0; i < 16; ++i) accW[i] = 0.f;
    float4 pa[4], pb[4];
    #pragma unroll
    for (int j = 0; j < 4; ++j) {
      int kal = j * 2 + khalf;
      pa[j] = ((const float4*)(arow + kal * 8))[0];
      pb[j] = ((const float4*)(arow + kal * 8))[1];
    }
    #pragma unroll
    for (int c = 0; c < 32; ++c) {
      int kal = c * 2 + khalf;
      union { unsigned short s[8]; bf16x8 v; } av;
      float4 a = pa[c & 3], b = pb[c & 3];
      av.s[0] = f2bf(a.x); av.s[1] = f2bf(a.y); av.s[2] = f2bf(a.z); av.s[3] = f2bf(a.w);
      av.s[4] = f2bf(b.x); av.s[5] = f2bf(b.y); av.s[6] = f2bf(b.z); av.s[7] = f2bf(b.w);
      if (c + 4 < 32) {
        int kn = (c + 4) * 2 + khalf;
        pa[c & 3] = ((const float4*)(arow + kn * 8))[0];
        pb[c & 3] = ((const float4*)(arow + kn * 8))[1];
      }
      int q = lane & 31;
      bf16x8 bp = *(const bf16x8*)(lds + BS_OFF + (((q << 6) + (kal ^ (q & 7))) << 4));
      accW = __builtin_amdgcn_mfma_f32_32x32x16_bf16(av.v, bp, accW, 0, 0, 0);
    }
    int q = lane & 31;
    #pragma unroll
    for (int r = 0; r < 16; ++r) {
      int row = (r & 3) + 8 * (r >> 2) + 4 * khalf + wm * 32;
      if (q < 16) {
        W1T[row * 17 + q] = accW[r];
      } else if (q == 16) {
        int g2 = (row & 3) * 512 + nt * 32 + (row >> 2);
        bT[row] = accW[r] + p.b_ih[g2] + p.b_hh[g2];
      }
    }
  }
  __syncthreads();

  // ---- read xg fragments + bias from LDS temps; convert h0 atoms
  union BW { unsigned short s[8]; bf16x8 v; } w0f, w1f;
  #pragma unroll
  for (int j = 0; j < 8; ++j) {
    w0f.s[j] = (unsigned short)f2bf(W1T[n0 * 17 + khalf * 8 + j]);
    w1f.s[j] = (unsigned short)f2bf(W1T[n1 * 17 + khalf * 8 + j]);
  }
  float biasr[2];
  biasr[0] = bT[wn * 64 + (lane & 31)];
  biasr[1] = bT[wn * 64 + 32 + (lane & 31)];
  {
    // h0 -> parity-1 atoms, exactly this block's store region
    const float* src = p.hh + (size_t)(m0 + pm) * 512 + nt * 32 + pj * 8;
    float4 f0 = ((const float4*)src)[0];
    float4 f1 = ((const float4*)src)[1];
    u64 lo = (u64)f2bf(f0.x) | ((u64)f2bf(f0.y) << 16)
           | ((u64)f2bf(f0.z) << 32) | ((u64)f2bf(f0.w) << 48);
    u64 hi = (u64)f2bf(f1.x) | ((u64)f2bf(f1.y) << 16)
           | ((u64)f2bf(f1.z) << 32) | ((u64)f2bf(f1.w) << 48);
    u64* hdst = (u64*)(p.hatom + 2097152 + mt * 131072);
    st8(hdst + (512 * nt + tid) * 2,     lo);
    st8(hdst + (512 * nt + tid) * 2 + 1, hi);
  }
  __syncthreads();                      // drains h0 st8 (vmcnt before barrier)
  if (tid == 0) st4(p.flags + mt * 32 + nt, 1u);

  // ---- Bs: w_hh slice -> bf16 atoms (overwrite init temps)
  for (int a = tid; a < 8192; a += NTHR) {
    int n = a >> 6, ka = a & 63;
    int grow = (n & 3) * 512 + nt * 32 + (n >> 2);
    const float* src = p.w_hh + (size_t)grow * 512 + ka * 8;
    uint4 v;
    v.x = f2bf(src[0]) | (f2bf(src[1]) << 16);
    v.y = f2bf(src[2]) | (f2bf(src[3]) << 16);
    v.z = f2bf(src[4]) | (f2bf(src[5]) << 16);
    v.w = f2bf(src[6]) | (f2bf(src[7]) << 16);
    *(uint4*)(lds + BS_OFF + ((size_t)(n * 64 + (ka ^ (n & 7)))) * 16) = v;
  }
  // hp_w1 atoms: atom (n<16, k8) = hp_w1[k8*8+j][n]
  for (int a = tid; a < 1024; a += NTHR) {
    int n = a >> 6, k8 = a & 63;
    const float* src = p.hp_w1 + (size_t)(k8 * 8) * 16 + n;
    uint4 v;
    v.x = f2bf(src[0])  | (f2bf(src[16]) << 16);
    v.y = f2bf(src[32]) | (f2bf(src[48]) << 16);
    v.z = f2bf(src[64]) | (f2bf(src[80]) << 16);
    v.w = f2bf(src[96]) | (f2bf(src[112]) << 16);
    *(uint4*)(lds + HPW_OFF + ((size_t)(n * 64 + (k8 ^ (n & 7)))) * 16) = v;
  }
  // c state (lanes with lane%4==0)
  float c_st[2][16];
  #pragma unroll
  for (int t2 = 0; t2 < 2; ++t2)
    #pragma unroll
    for (int r = 0; r < 16; ++r) c_st[t2][r] = 0.f;
  if ((lane & 3) == 0) {
    #pragma unroll
    for (int t2 = 0; t2 < 2; ++t2) {
      int jj = (wn * 64 + t2 * 32 + (lane & 31)) >> 2;
      #pragma unroll
      for (int r = 0; r < 16; ++r) {
        int row = (r & 3) + 8 * (r >> 2) + 4 * khalf + wm * 32;
        c_st[t2][r] = p.ch0[(size_t)(m0 + row) * 512 + nt * 32 + jj];
      }
    }
  }
  __syncthreads();

  float sA2q = 0.f, bA2q = 0.f;
  if ((lane & 31) < 16) { sA2q = prm[32 + (lane & 31)]; bA2q = prm[48 + (lane & 31)]; }
  const unsigned* flp = p.flags + mt * 32 + (lane & 15);
  int tokr = 0;                         // consumer-side cached token

  // ================= main loop =================
  for (int t = 0; t < TSEQ; ++t) {
    // ---------- GEMM over h_t with incremental region gating ----------
    f32x16 acc0, acc1, accP;
    #pragma unroll
    for (int i = 0; i < 16; ++i) { acc0[i] = 0.f; acc1[i] = 0.f; accP[i] = 0.f; }
    {
      const char* abase = p.hatom + (size_t)((t + 1) & 1) * 2097152 + mt * 131072
                          + (wm * 64 + lane) * 16;
      int pfx = 0;                      // wid0's per-step ready prefix
      GATE(4, t);                       // regions 0..3 for the initial window
      vm_drain();                       // clean vmcnt baseline
      u32x4 pre[DEPTH];
      #pragma unroll
      for (int c = 0; c < DEPTH; ++c) pre[c] = ld16_dev(abase + c * 4096);
      union AB { u32x4 u; bf16x8 v; };
      #pragma unroll
      for (int c = 0; c < 32; ++c) {
        GATE(REQC(c), t);               // region for this iter's prefetch
        switch (c) {
          default: WAITV(7); break;
          case 25: WAITV(6); break;
          case 26: WAITV(5); break;
          case 27: WAITV(4); break;
          case 28: WAITV(3); break;
          case 29: WAITV(2); break;
          case 30: WAITV(1); break;
          case 31: WAITV(0); break;
        }
        AB u;
        u.u = pre[c & (DEPTH - 1)];
        if (c + DEPTH < 32)
          pre[c & (DEPTH - 1)] = ld16_dev(abase + (c + DEPTH) * 4096);
        int kal = c * 2 + khalf;
        bf16x8 b0 = *(const bf16x8*)(lds + BS_OFF + (((n0 << 6) + (kal ^ (n0 & 7))) << 4));
        bf16x8 b1 = *(const bf16x8*)(lds + BS_OFF + (((n1 << 6) + (kal ^ (n1 & 7))) << 4));
        acc0 = __builtin_amdgcn_mfma_f32_32x32x16_bf16(u.v, b0, acc0, 0, 0, 0);
        acc1 = __builtin_amdgcn_mfma_f32_32x32x16_bf16(u.v, b1, acc1, 0, 0, 0);
        if (wn == 0) {
          bf16x8 bp = {};
          if ((lane & 31) < 16)
            bp = *(const bf16x8*)(lds + HPW_OFF
                  + ((((lane & 31) << 6) + (kal ^ (lane & 7))) << 4));
          accP = __builtin_amdgcn_mfma_f32_32x32x16_bf16(u.v, bp, accP, 0, 0, 0);
        }
      }
    }

    // ---------- P -> h2s (wn==0 waves) ----------
    if (t > 0) {
      if (wn == 0 && (lane & 31) < 16) {
        int q = lane & 31;
        #pragma unroll
        for (int r = 0; r < 16; ++r) {
          int row = (r & 3) + 8 * (r >> 2) + 4 * khalf + wm * 32;
          h2s[row * 20 + q] = fmaxf(accP[r] * sA2q + bA2q, 0.f);
        }
      }
      __syncthreads();
    }

    // ---------- merged lp + h1 (threads < 256; DPP pair swap) ----------
    if (tid < 256) {
      int m = tid >> 1, c = tid & 1;
      float lp0, lp1;
      if (t > 0) {
        float a2 = prm[128 + c];
        const float4* hrow = (const float4*)(lds + UNI_OFF + m * 80);
        #pragma unroll
        for (int g4 = 0; g4 < 4; ++g4) {
          float4 v = hrow[g4];
          a2 += v.x * prm[96 + (g4 * 4 + 0) * 2 + c];
          a2 += v.y * prm[96 + (g4 * 4 + 1) * 2 + c];
          a2 += v.z * prm[96 + (g4 * 4 + 2) * 2 + c];
          a2 += v.w * prm[96 + (g4 * 4 + 3) * 2 + c];
        }
        float lpv = 1.f / (1.f + __expf(-(a2 + lps[tid])));
        lps[tid] = lpv;
        if (nt == 0)
          p.out[((size_t)(t - 1) * BATCH + m0 + m) * 2 + c] = lpv;
        float other = QB(lpv, 0xB1);                   // swap within lane pair
        lp0 = c ? other : lpv;
        lp1 = c ? lpv : other;
      } else {
        lp0 = lps[m * 2];
        lp1 = lps[m * 2 + 1];
      }
      // h1 for q = c*8 .. c*8+7, packed 16 B store
      u64 hq[2];
      #pragma unroll
      for (int half = 0; half < 2; ++half) {
        u64 w = 0;
        #pragma unroll
        for (int i = 0; i < 4; ++i) {
          int q = c * 8 + half * 4 + i;
          float z = lp0 * prm[64 + q] + lp1 * prm[80 + q];
          w |= (u64)f2bf(fmaxf(z * prm[q] + prm[16 + q], 0.f)) << (16 * i);
        }
        hq[half] = w;
      }
      u64* hd = (u64*)(lds + H1_OFF + m * 32 + c * 16);
      hd[0] = hq[0];
      hd[1] = hq[1];
    }
    __syncthreads();

    // ---------- xg contribution (last MFMA) ----------
    {
      bf16x8 a1 = *(const bf16x8*)(lds + H1_OFF + (wm * 32 + (lane & 31)) * 32 + khalf * 16);
      acc0 = __builtin_amdgcn_mfma_f32_32x32x16_bf16(a1, w0f.v, acc0, 0, 0, 0);
      acc1 = __builtin_amdgcn_mfma_f32_32x32x16_bf16(a1, w1f.v, acc1, 0, 0, 0);
    }

    // ---------- epilogue: LSTM cell update ----------
    #pragma unroll
    for (int t2 = 0; t2 < 2; ++t2) {
      float bias = biasr[t2];
      int jj = (wn * 64 + t2 * 32 + (lane & 31)) >> 2;
      float act[16];
      const f32x16& A = (t2 == 0) ? acc0 : acc1;
      #pragma unroll
      for (int r = 0; r < 16; ++r) {
        float v = A[r] + bias;
        float vv = (gate == 2) ? 2.f * v : v;
        float sg = 1.f / (1.f + __expf(-vv));
        act[r] = (gate == 2) ? 2.f * sg - 1.f : sg;
      }
      #pragma unroll
      for (int r = 0; r < 16; ++r) {
        float iv = QB(act[r], 0x00);
        float fv = QB(act[r], 0x55);
        float gv = QB(act[r], 0xAA);
        float ov = QB(act[r], 0xFF);
        float cn = fv * c_st[t2][r] + iv * gv;
        c_st[t2][r] = cn;
        float th = 2.f / (1.f + __expf(-2.f * cn)) - 1.f;
        float hn = ov * th;
        if ((lane & 3) == 0) {
          int row = (r & 3) + 8 * (r >> 2) + 4 * khalf + wm * 32;
          hPsh[row * 36 + jj] = (unsigned short)f2bf(hn);
        }
      }
    }
    __syncthreads();

    // ---------- coalesced h-atom stores (sc0sc1 write-through) + flag ----------
    {
      const u64* hp8 = (const u64*)(lds + UNI_OFF + pm * 72 + pj * 16);
      u64* hdst = (u64*)(p.hatom + (size_t)(t & 1) * 2097152 + mt * 131072);
      st8(hdst + (512 * nt + tid) * 2,     hp8[0]);
      st8(hdst + (512 * nt + tid) * 2 + 1, hp8[1]);
    }
    __syncthreads();   // implicit vmcnt(0) drains the sc1 stores
    if (tid == 0) st4(p.flags + mt * 32 + nt, (unsigned)(t + 2));
  }

  // ---------- tail (t=32): P(h_32) only -> lp_32 -> out[31] ----------
  {
    f32x16 accP;
    #pragma unroll
    for (int i = 0; i < 16; ++i) accP[i] = 0.f;
    if (wn == 0) {
      const char* abase = p.hatom + 2097152 + mt * 131072 + (wm * 64 + lane) * 16;
      int pfx = 0;
      GATE(4, TSEQ);
      vm_drain();
      u32x4 pre[DEPTH];
      #pragma unroll
      for (int c = 0; c < DEPTH; ++c) pre[c] = ld16_dev(abase + c * 4096);
      union AB { u32x4 u; bf16x8 v; };
      #pragma unroll
      for (int c = 0; c < 32; ++c) {
        GATE(REQC(c), TSEQ);
        switch (c) {
          default: WAITV(7); break;
          case 25: WAITV(6); break;
          case 26: WAITV(5); break;
          case 27: WAITV(4); break;
          case 28: WAITV(3); break;
          case 29: WAITV(2); break;
          case 30: WAITV(1); break;
          case 31: WAITV(0); break;
        }
        AB u;
        u.u = pre[c & (DEPTH - 1)];
        if (c + DEPTH < 32)
          pre[c & (DEPTH - 1)] = ld16_dev(abase + (c + DEPTH) * 4096);
        int kal = c * 2 + khalf;
        bf16x8 bp = {};
        if ((lane & 31) < 16)
          bp = *(const bf16x8*)(lds + HPW_OFF
                + ((((lane & 31) << 6) + (kal ^ (lane & 7))) << 4));
        accP = __builtin_amdgcn_mfma_f32_32x32x16_bf16(u.v, bp, accP, 0, 0, 0);
      }
      if ((lane & 31) < 16) {
        int q = lane & 31;
        #pragma unroll
        for (int r = 0; r < 16; ++r) {
          int row = (r & 3) + 8 * (r >> 2) + 4 * khalf + wm * 32;
          h2s[row * 20 + q] = fmaxf(accP[r] * sA2q + bA2q, 0.f);
        }
      }
    }
    __syncthreads();
    if (tid < 256 && nt == 0) {
      int m = tid >> 1, c = tid & 1;
      float a2 = prm[128 + c];
      const float4* hrow = (const float4*)(lds + UNI_OFF + m * 80);
      #pragma unroll
      for (int g4 = 0; g4 < 4; ++g4) {
        float4 v = hrow[g4];
        a2 += v.x * prm[96 + (g4 * 4 + 0) * 2 + c];
        a2 += v.y * prm[96 + (g4 * 4 + 1) * 2 + c];
        a2 += v.z * prm[96 + (g4 * 4 + 2) * 2 + c];
        a2 += v.w * prm[96 + (g4 * 4 + 3) * 2 + c];
      }
      float lpv = 1.f / (1.f + __expf(-(a2 + lps[tid])));
      p.out[((size_t)(TSEQ - 1) * BATCH + m0 + m) * 2 + c] = lpv;
    }
  }
}

// ---------------------------------------------------------------------------
extern "C" void kernel_launch(void* const* d_in, const int* in_sizes, int n_in,
                              void* d_out, int out_size, void* d_ws, size_t ws_size,
                              hipStream_t stream) {
  char* ws = (char*)d_ws;
  KParams kp;
  kp.last_pos = (const float*)d_in[0];
  kp.hh    = (const float*)d_in[1];
  kp.ch0   = (const float*)d_in[2];
  kp.se_w1 = (const float*)d_in[3];
  kp.se_b1 = (const float*)d_in[4];
  kp.se_g  = (const float*)d_in[5];
  kp.se_bt = (const float*)d_in[6];
  kp.se_m  = (const float*)d_in[7];
  kp.se_v  = (const float*)d_in[8];
  kp.se_w2 = (const float*)d_in[9];
  kp.se_b2 = (const float*)d_in[10];
  kp.w_ih  = (const float*)d_in[11];
  kp.w_hh  = (const float*)d_in[12];
  kp.b_ih  = (const float*)d_in[13];
  kp.b_hh  = (const float*)d_in[14];
  kp.hp_w1 = (const float*)d_in[15];
  kp.hp_b1 = (const float*)d_in[16];
  kp.hp_g  = (const float*)d_in[17];
  kp.hp_bt = (const float*)d_in[18];
  kp.hp_m  = (const float*)d_in[19];
  kp.hp_v  = (const float*)d_in[20];
  kp.hp_w2 = (const float*)d_in[21];
  kp.hp_b2 = (const float*)d_in[22];
  kp.flags = (unsigned*)(ws + WS_FLAGS);
  kp.hatom = ws + WS_HATOM;
  kp.out   = (float*)d_out;

  (void)hipMemsetAsync(ws + WS_FLAGS, 0, 2048, stream);
  (void)hipFuncSetAttribute((const void*)decoder_persist,
                            hipFuncAttributeMaxDynamicSharedMemorySize, LDS_TOTAL);
  decoder_persist<<<dim3(NBLK), dim3(NTHR), LDS_TOTAL, stream>>>(kp);
}

// Round 11
// 527.227 us; speedup vs baseline: 1.1562x; 1.0968x over previous
//
#include <hip/hip_runtime.h>

// ============================================================================
// Decoder_70437463654609: 32-step LSTM recurrence, B=2048 H=512 HID=16.
// R19 = R12 verbatim (proven best: 477us counter-time, passed twice).
// Session ledger: R10 473 / R12 477 / R13 (XCD-L2 data, -89% HBM) 502 /
// R17 (breg0 hoist, VGPR spill) 520 / R18 (incremental gating) 535.
// Conclusion: step time is issue+dependency-bound at reduced effective clock;
// memory path, coherence scope, sync granularity, and register allocation all
// falsified as levers. This is the structural floor for this decomposition.
//  * agent-scope __hip_atomic flags/h-stores (device-coherent, hang-free),
//  * system-scope (sc0 sc1) A-loads, counted s_waitcnt vmcnt DEPTH-8 window,
//  * no per-step cache invalidates.
// Graph = memset(flags) + persist only.
// ============================================================================

#define TSEQ  32
#define BATCH 2048
#define HDIM  512
#define NBLK  256
#define NTHR  512
#define DEPTH 8

typedef __bf16 bf16x8 __attribute__((ext_vector_type(8)));
typedef float  f32x16 __attribute__((ext_vector_type(16)));
typedef unsigned u32x4 __attribute__((ext_vector_type(4)));
typedef unsigned long long u64;

// ---- LDS layout (byte offsets), total 163,360 <= 163,840 ----
#define BS_OFF     0          // Bs: w_hh [128 n][64 k8 x 16B] swz (131072); init: B-atoms(32KB)+W1T+bT
#define HPW_OFF    131072     // hp_w1 atoms [16 n][64 k8 x 16B] swz (16384)
#define UNI_OFF    147456     // union: h2s [128][20] f32 (10240) | hP bf16 [128][36] (9216)
#define H1_OFF     157696     // h1s [128 m][16 bf16] stride 32 B (4096)
#define LPS_OFF    161792     // lps [128][2] f32 (1024)
#define PRM_OFF    162816     // folded params (130 f32) (544)
#define LDS_TOTAL  163360
// init-phase temporaries inside the Bs region:
#define W1T_OFF    32768      // [128][17] f32 (8704)
#define BT_OFF     41472      // [128] f32 (512)

// ---- workspace layout (bytes) ----
#define WS_FLAGS  0                        // 16 groups x 128 B (memset to 0)
#define WS_HATOM  2048                     // 2 x (16 mt x 128 KB) h atoms

__device__ __forceinline__ unsigned f2bf(float f) {   // RNE f32->bf16 (low 16)
  unsigned u = __float_as_uint(f);
  u += 0x7fffu + ((u >> 16) & 1u);
  return u >> 16;
}
// relaxed agent-scope ops (device-coherent via MALL) — proven hang-free
__device__ __forceinline__ void st8(void* p, u64 v) {
  __hip_atomic_store((u64*)p, v, __ATOMIC_RELAXED, __HIP_MEMORY_SCOPE_AGENT);
}
__device__ __forceinline__ unsigned ld4(const unsigned* p) {
  return __hip_atomic_load(p, __ATOMIC_RELAXED, __HIP_MEMORY_SCOPE_AGENT);
}
__device__ __forceinline__ void st4(unsigned* p, unsigned v) {
  __hip_atomic_store(p, v, __ATOMIC_RELAXED, __HIP_MEMORY_SCOPE_AGENT);
}
// system-scope bulk load for the h-atom exchange; result NOT ready until an
// explicit s_waitcnt vmcnt — compiler does not track it.
__device__ __forceinline__ u32x4 ld16_dev(const void* p) {
  u32x4 r;
  asm volatile("global_load_dwordx4 %0, %1, off sc0 sc1"
               : "=&v"(r) : "v"(p) : "memory");
  return r;
}
__device__ __forceinline__ void vm_drain() {
  asm volatile("s_waitcnt vmcnt(0)" ::: "memory");
}
// counted vmem wait + hard scheduling fence (rule #18: keep MFMA below it)
#define WAITV(n) do { asm volatile("s_waitcnt vmcnt(" #n ")" ::: "memory"); \
                      __builtin_amdgcn_sched_barrier(0); } while (0)

// quad-perm broadcasts / swaps
#define QB(x, imm) __uint_as_float((unsigned)__builtin_amdgcn_mov_dpp((int)__float_as_uint(x), imm, 0xF, 0xF, true))

struct KParams {
  const float *last_pos, *hh, *ch0, *w_hh, *w_ih, *b_ih, *b_hh;
  const float *se_w1, *se_b1, *se_g, *se_bt, *se_m, *se_v, *se_w2, *se_b2;
  const float *hp_w1, *hp_b1, *hp_g, *hp_bt, *hp_m, *hp_v, *hp_w2, *hp_b2;
  char* hatom;            // 2 parities x 2 MB
  unsigned* flags;        // 16 groups x 32 u32
  float* out;
};

// ---------------------------------------------------------------------------
// Persistent kernel. 256 blocks x 512 threads, 1 block/CU (plain launch).
// Block (mt, nt): rows [mt*128,+128), local n = 4*jj + gate.
// ---------------------------------------------------------------------------
__global__ __launch_bounds__(NTHR, 2) void decoder_persist(KParams p) {
  extern __shared__ char lds[];
  const int tid  = threadIdx.x;
  const int lane = tid & 63;
  const int wid  = tid >> 6;
  const int wm   = wid >> 1;
  const int wn   = wid & 1;
  const int mt   = blockIdx.x >> 4;
  const int nt   = blockIdx.x & 15;
  const int m0   = mt * 128;

  float* prm = (float*)(lds + PRM_OFF);
  float* lps = (float*)(lds + LPS_OFF);
  float* h2s = (float*)(lds + UNI_OFF);                    // stride 20 f32
  unsigned short* hPsh = (unsigned short*)(lds + UNI_OFF); // stride 36 u16
  float* W1T = (float*)(lds + W1T_OFF);                    // [128][17]
  float* bT  = (float*)(lds + BT_OFF);                     // [128]

  const int n0 = wn * 64 + (lane & 31);
  const int n1 = n0 + 32;
  const int gate = lane & 3;
  const int khalf = lane >> 5;
  const int pj = ((tid >> 8) << 1) | ((tid >> 5) & 1);
  const int pm = ((tid >> 6) & 3) * 32 + (tid & 31);

  // ================= one-time init =================
  if (tid < 16) {
    int q = tid;
    float sA = p.se_g[q] * rsqrtf(p.se_v[q] + 1e-5f);
    prm[q]      = sA;
    prm[16 + q] = (p.se_b1[q] - p.se_m[q]) * sA + p.se_bt[q];
    float hA = p.hp_g[q] * rsqrtf(p.hp_v[q] + 1e-5f);
    prm[32 + q] = hA;
    prm[48 + q] = (p.hp_b1[q] - p.hp_m[q]) * hA + p.hp_bt[q];
  }
  if (tid < 32) { prm[64 + tid] = p.se_w1[tid]; prm[96 + tid] = p.hp_w2[tid]; }
  if (tid < 2)  { prm[128 + tid] = p.hp_b2[tid]; }
  if (tid < 256) lps[tid] = p.last_pos[(size_t)m0 * 2 + tid];

  // ---- stage init B-atoms: cols 0..15 = se_w2 rows, 16 = se_b2, 17..31 = 0
  for (int a = tid; a < 2048; a += NTHR) {
    int n = a >> 6, k8 = a & 63;
    uint4 v = {0, 0, 0, 0};
    if (n <= 16) {
      const float* src = (n < 16) ? (p.se_w2 + (size_t)n * 512 + k8 * 8)
                                  : (p.se_b2 + k8 * 8);
      v.x = f2bf(src[0]) | (f2bf(src[1]) << 16);
      v.y = f2bf(src[2]) | (f2bf(src[3]) << 16);
      v.z = f2bf(src[4]) | (f2bf(src[5]) << 16);
      v.w = f2bf(src[6]) | (f2bf(src[7]) << 16);
    }
    *(uint4*)(lds + BS_OFF + ((size_t)(n * 64 + (k8 ^ (n & 7)))) * 16) = v;
  }
  __syncthreads();

  // ---- init-MFMA: W1f[128 gate-rows][16] = w_ih_slice @ se_w2^T (+bias col 16)
  if ((wid & 1) == 0) {
    int rloc = wm * 32 + (lane & 31);
    int grow = (rloc & 3) * 512 + nt * 32 + (rloc >> 2);
    const float* arow = p.w_ih + (size_t)grow * 512;
    f32x16 accW;
    #pragma unroll
    for (int i = 0; i < 16; ++i) accW[i] = 0.f;
    float4 pa[4], pb[4];
    #pragma unroll
    for (int j = 0; j < 4; ++j) {
      int kal = j * 2 + khalf;
      pa[j] = ((const float4*)(arow + kal * 8))[0];
      pb[j] = ((const float4*)(arow + kal * 8))[1];
    }
    #pragma unroll
    for (int c = 0; c < 32; ++c) {
      int kal = c * 2 + khalf;
      union { unsigned short s[8]; bf16x8 v; } av;
      float4 a = pa[c & 3], b = pb[c & 3];
      av.s[0] = f2bf(a.x); av.s[1] = f2bf(a.y); av.s[2] = f2bf(a.z); av.s[3] = f2bf(a.w);
      av.s[4] = f2bf(b.x); av.s[5] = f2bf(b.y); av.s[6] = f2bf(b.z); av.s[7] = f2bf(b.w);
      if (c + 4 < 32) {
        int kn = (c + 4) * 2 + khalf;
        pa[c & 3] = ((const float4*)(arow + kn * 8))[0];
        pb[c & 3] = ((const float4*)(arow + kn * 8))[1];
      }
      int q = lane & 31;
      bf16x8 bp = *(const bf16x8*)(lds + BS_OFF + (((q << 6) + (kal ^ (q & 7))) << 4));
      accW = __builtin_amdgcn_mfma_f32_32x32x16_bf16(av.v, bp, accW, 0, 0, 0);
    }
    int q = lane & 31;
    #pragma unroll
    for (int r = 0; r < 16; ++r) {
      int row = (r & 3) + 8 * (r >> 2) + 4 * khalf + wm * 32;
      if (q < 16) {
        W1T[row * 17 + q] = accW[r];
      } else if (q == 16) {
        int g2 = (row & 3) * 512 + nt * 32 + (row >> 2);
        bT[row] = accW[r] + p.b_ih[g2] + p.b_hh[g2];
      }
    }
  }
  __syncthreads();

  // ---- read xg fragments + bias from LDS temps; convert h0 atoms
  union BW { unsigned short s[8]; bf16x8 v; } w0f, w1f;
  #pragma unroll
  for (int j = 0; j < 8; ++j) {
    w0f.s[j] = (unsigned short)f2bf(W1T[n0 * 17 + khalf * 8 + j]);
    w1f.s[j] = (unsigned short)f2bf(W1T[n1 * 17 + khalf * 8 + j]);
  }
  float biasr[2];
  biasr[0] = bT[wn * 64 + (lane & 31)];
  biasr[1] = bT[wn * 64 + 32 + (lane & 31)];
  {
    // h0 -> parity-1 atoms, exactly this block's store region
    const float* src = p.hh + (size_t)(m0 + pm) * 512 + nt * 32 + pj * 8;
    float4 f0 = ((const float4*)src)[0];
    float4 f1 = ((const float4*)src)[1];
    u64 lo = (u64)f2bf(f0.x) | ((u64)f2bf(f0.y) << 16)
           | ((u64)f2bf(f0.z) << 32) | ((u64)f2bf(f0.w) << 48);
    u64 hi = (u64)f2bf(f1.x) | ((u64)f2bf(f1.y) << 16)
           | ((u64)f2bf(f1.z) << 32) | ((u64)f2bf(f1.w) << 48);
    u64* hdst = (u64*)(p.hatom + 2097152 + mt * 131072);
    st8(hdst + (512 * nt + tid) * 2,     lo);
    st8(hdst + (512 * nt + tid) * 2 + 1, hi);
  }
  __syncthreads();                      // drains h0 st8 (vmcnt before barrier)
  if (tid == 0) st4(p.flags + mt * 32 + nt, 1u);

  // ---- Bs: w_hh slice -> bf16 atoms (overwrite init temps)
  for (int a = tid; a < 8192; a += NTHR) {
    int n = a >> 6, ka = a & 63;
    int grow = (n & 3) * 512 + nt * 32 + (n >> 2);
    const float* src = p.w_hh + (size_t)grow * 512 + ka * 8;
    uint4 v;
    v.x = f2bf(src[0]) | (f2bf(src[1]) << 16);
    v.y = f2bf(src[2]) | (f2bf(src[3]) << 16);
    v.z = f2bf(src[4]) | (f2bf(src[5]) << 16);
    v.w = f2bf(src[6]) | (f2bf(src[7]) << 16);
    *(uint4*)(lds + BS_OFF + ((size_t)(n * 64 + (ka ^ (n & 7)))) * 16) = v;
  }
  // hp_w1 atoms: atom (n<16, k8) = hp_w1[k8*8+j][n]
  for (int a = tid; a < 1024; a += NTHR) {
    int n = a >> 6, k8 = a & 63;
    const float* src = p.hp_w1 + (size_t)(k8 * 8) * 16 + n;
    uint4 v;
    v.x = f2bf(src[0])  | (f2bf(src[16]) << 16);
    v.y = f2bf(src[32]) | (f2bf(src[48]) << 16);
    v.z = f2bf(src[64]) | (f2bf(src[80]) << 16);
    v.w = f2bf(src[96]) | (f2bf(src[112]) << 16);
    *(uint4*)(lds + HPW_OFF + ((size_t)(n * 64 + (k8 ^ (n & 7)))) * 16) = v;
  }
  // c state (lanes with lane%4==0)
  float c_st[2][16];
  #pragma unroll
  for (int t2 = 0; t2 < 2; ++t2)
    #pragma unroll
    for (int r = 0; r < 16; ++r) c_st[t2][r] = 0.f;
  if ((lane & 3) == 0) {
    #pragma unroll
    for (int t2 = 0; t2 < 2; ++t2) {
      int jj = (wn * 64 + t2 * 32 + (lane & 31)) >> 2;
      #pragma unroll
      for (int r = 0; r < 16; ++r) {
        int row = (r & 3) + 8 * (r >> 2) + 4 * khalf + wm * 32;
        c_st[t2][r] = p.ch0[(size_t)(m0 + row) * 512 + nt * 32 + jj];
      }
    }
  }
  __syncthreads();

  float sA2q = 0.f, bA2q = 0.f;
  if ((lane & 31) < 16) { sA2q = prm[32 + (lane & 31)]; bA2q = prm[48 + (lane & 31)]; }
  const unsigned* fl = p.flags + mt * 32 + (lane & 15);

  // ================= main loop =================
  for (int t = 0; t < TSEQ; ++t) {
    if (wid == 0) {
      while (!__all((int)(ld4(fl) >= (unsigned)(t + 1))))
        __builtin_amdgcn_s_sleep(2);
      // NO l2_inv: A-atoms are read at system scope (sc0 sc1), MALL-coherent
    }
    __syncthreads();

    // ---------- GEMM over h_t: gates (acc0,acc1) + P (accP, wn==0) ----------
    f32x16 acc0, acc1, accP;
    #pragma unroll
    for (int i = 0; i < 16; ++i) { acc0[i] = 0.f; acc1[i] = 0.f; accP[i] = 0.f; }
    {
      const char* abase = p.hatom + (size_t)((t + 1) & 1) * 2097152 + mt * 131072
                          + (wm * 64 + lane) * 16;
      vm_drain();                               // clean vmcnt baseline
      u32x4 pre[DEPTH];
      #pragma unroll
      for (int c = 0; c < DEPTH; ++c) pre[c] = ld16_dev(abase + c * 4096);
      union AB { u32x4 u; bf16x8 v; };
      #pragma unroll
      for (int c = 0; c < 32; ++c) {
        // wait for load c: N = (loads issued) - (c+1), capped by window
        switch (c) {
          default: WAITV(7); break;
          case 25: WAITV(6); break;
          case 26: WAITV(5); break;
          case 27: WAITV(4); break;
          case 28: WAITV(3); break;
          case 29: WAITV(2); break;
          case 30: WAITV(1); break;
          case 31: WAITV(0); break;
        }
        AB u;
        u.u = pre[c & (DEPTH - 1)];
        if (c + DEPTH < 32)
          pre[c & (DEPTH - 1)] = ld16_dev(abase + (c + DEPTH) * 4096);
        int kal = c * 2 + khalf;
        bf16x8 b0 = *(const bf16x8*)(lds + BS_OFF + (((n0 << 6) + (kal ^ (n0 & 7))) << 4));
        bf16x8 b1 = *(const bf16x8*)(lds + BS_OFF + (((n1 << 6) + (kal ^ (n1 & 7))) << 4));
        acc0 = __builtin_amdgcn_mfma_f32_32x32x16_bf16(u.v, b0, acc0, 0, 0, 0);
        acc1 = __builtin_amdgcn_mfma_f32_32x32x16_bf16(u.v, b1, acc1, 0, 0, 0);
        if (wn == 0) {
          bf16x8 bp = {};
          if ((lane & 31) < 16)
            bp = *(const bf16x8*)(lds + HPW_OFF
                  + ((((lane & 31) << 6) + (kal ^ (lane & 7))) << 4));
          accP = __builtin_amdgcn_mfma_f32_32x32x16_bf16(u.v, bp, accP, 0, 0, 0);
        }
      }
    }

    // ---------- P -> h2s (wn==0 waves) ----------
    if (t > 0) {
      if (wn == 0 && (lane & 31) < 16) {
        int q = lane & 31;
        #pragma unroll
        for (int r = 0; r < 16; ++r) {
          int row = (r & 3) + 8 * (r >> 2) + 4 * khalf + wm * 32;
          h2s[row * 20 + q] = fmaxf(accP[r] * sA2q + bA2q, 0.f);
        }
      }
      __syncthreads();
    }

    // ---------- merged lp + h1 (threads < 256; DPP pair swap) ----------
    if (tid < 256) {
      int m = tid >> 1, c = tid & 1;
      float lp0, lp1;
      if (t > 0) {
        float a2 = prm[128 + c];
        const float4* hrow = (const float4*)(lds + UNI_OFF + m * 80);
        #pragma unroll
        for (int g4 = 0; g4 < 4; ++g4) {
          float4 v = hrow[g4];
          a2 += v.x * prm[96 + (g4 * 4 + 0) * 2 + c];
          a2 += v.y * prm[96 + (g4 * 4 + 1) * 2 + c];
          a2 += v.z * prm[96 + (g4 * 4 + 2) * 2 + c];
          a2 += v.w * prm[96 + (g4 * 4 + 3) * 2 + c];
        }
        float lpv = 1.f / (1.f + __expf(-(a2 + lps[tid])));
        lps[tid] = lpv;
        if (nt == 0)
          p.out[((size_t)(t - 1) * BATCH + m0 + m) * 2 + c] = lpv;
        float other = QB(lpv, 0xB1);                   // swap within lane pair
        lp0 = c ? other : lpv;
        lp1 = c ? lpv : other;
      } else {
        lp0 = lps[m * 2];
        lp1 = lps[m * 2 + 1];
      }
      // h1 for q = c*8 .. c*8+7, packed 16 B store
      u64 hq[2];
      #pragma unroll
      for (int half = 0; half < 2; ++half) {
        u64 w = 0;
        #pragma unroll
        for (int i = 0; i < 4; ++i) {
          int q = c * 8 + half * 4 + i;
          float z = lp0 * prm[64 + q] + lp1 * prm[80 + q];
          w |= (u64)f2bf(fmaxf(z * prm[q] + prm[16 + q], 0.f)) << (16 * i);
        }
        hq[half] = w;
      }
      u64* hd = (u64*)(lds + H1_OFF + m * 32 + c * 16);
      hd[0] = hq[0];
      hd[1] = hq[1];
    }
    __syncthreads();

    // ---------- xg contribution (last MFMA) ----------
    {
      bf16x8 a1 = *(const bf16x8*)(lds + H1_OFF + (wm * 32 + (lane & 31)) * 32 + khalf * 16);
      acc0 = __builtin_amdgcn_mfma_f32_32x32x16_bf16(a1, w0f.v, acc0, 0, 0, 0);
      acc1 = __builtin_amdgcn_mfma_f32_32x32x16_bf16(a1, w1f.v, acc1, 0, 0, 0);
    }

    // ---------- epilogue: LSTM cell update ----------
    #pragma unroll
    for (int t2 = 0; t2 < 2; ++t2) {
      float bias = biasr[t2];
      int jj = (wn * 64 + t2 * 32 + (lane & 31)) >> 2;
      float act[16];
      const f32x16& A = (t2 == 0) ? acc0 : acc1;
      #pragma unroll
      for (int r = 0; r < 16; ++r) {
        float v = A[r] + bias;
        float vv = (gate == 2) ? 2.f * v : v;
        float sg = 1.f / (1.f + __expf(-vv));
        act[r] = (gate == 2) ? 2.f * sg - 1.f : sg;
      }
      #pragma unroll
      for (int r = 0; r < 16; ++r) {
        float iv = QB(act[r], 0x00);
        float fv = QB(act[r], 0x55);
        float gv = QB(act[r], 0xAA);
        float ov = QB(act[r], 0xFF);
        float cn = fv * c_st[t2][r] + iv * gv;
        c_st[t2][r] = cn;
        float th = 2.f / (1.f + __expf(-2.f * cn)) - 1.f;
        float hn = ov * th;
        if ((lane & 3) == 0) {
          int row = (r & 3) + 8 * (r >> 2) + 4 * khalf + wm * 32;
          hPsh[row * 36 + jj] = (unsigned short)f2bf(hn);
        }
      }
    }
    __syncthreads();

    // ---------- coalesced h-atom stores (sc0sc1 write-through) + flag ----------
    {
      const u64* hp8 = (const u64*)(lds + UNI_OFF + pm * 72 + pj * 16);
      u64* hdst = (u64*)(p.hatom + (size_t)(t & 1) * 2097152 + mt * 131072);
      st8(hdst + (512 * nt + tid) * 2,     hp8[0]);
      st8(hdst + (512 * nt + tid) * 2 + 1, hp8[1]);
    }
    __syncthreads();   // implicit vmcnt(0) drains the sc1 stores
    if (tid == 0) st4(p.flags + mt * 32 + nt, (unsigned)(t + 2));
  }

  // ---------- tail (t=32): P(h_32) only -> lp_32 -> out[31] ----------
  {
    if (wid == 0) {
      while (!__all((int)(ld4(fl) >= (unsigned)(TSEQ + 1))))
        __builtin_amdgcn_s_sleep(2);
    }
    __syncthreads();
    f32x16 accP;
    #pragma unroll
    for (int i = 0; i < 16; ++i) accP[i] = 0.f;
    if (wn == 0) {
      const char* abase = p.hatom + 2097152 + mt * 131072 + (wm * 64 + lane) * 16;
      vm_drain();
      u32x4 pre[DEPTH];
      #pragma unroll
      for (int c = 0; c < DEPTH; ++c) pre[c] = ld16_dev(abase + c * 4096);
      union AB { u32x4 u; bf16x8 v; };
      #pragma unroll
      for (int c = 0; c < 32; ++c) {
        switch (c) {
          default: WAITV(7); break;
          case 25: WAITV(6); break;
          case 26: WAITV(5); break;
          case 27: WAITV(4); break;
          case 28: WAITV(3); break;
          case 29: WAITV(2); break;
          case 30: WAITV(1); break;
          case 31: WAITV(0); break;
        }
        AB u;
        u.u = pre[c & (DEPTH - 1)];
        if (c + DEPTH < 32)
          pre[c & (DEPTH - 1)] = ld16_dev(abase + (c + DEPTH) * 4096);
        int kal = c * 2 + khalf;
        bf16x8 bp = {};
        if ((lane & 31) < 16)
          bp = *(const bf16x8*)(lds + HPW_OFF
                + ((((lane & 31) << 6) + (kal ^ (lane & 7))) << 4));
        accP = __builtin_amdgcn_mfma_f32_32x32x16_bf16(u.v, bp, accP, 0, 0, 0);
      }
      if ((lane & 31) < 16) {
        int q = lane & 31;
        #pragma unroll
        for (int r = 0; r < 16; ++r) {
          int row = (r & 3) + 8 * (r >> 2) + 4 * khalf + wm * 32;
          h2s[row * 20 + q] = fmaxf(accP[r] * sA2q + bA2q, 0.f);
        }
      }
    }
    __syncthreads();
    if (tid < 256 && nt == 0) {
      int m = tid >> 1, c = tid & 1;
      float a2 = prm[128 + c];
      const float4* hrow = (const float4*)(lds + UNI_OFF + m * 80);
      #pragma unroll
      for (int g4 = 0; g4 < 4; ++g4) {
        float4 v = hrow[g4];
        a2 += v.x * prm[96 + (g4 * 4 + 0) * 2 + c];
        a2 += v.y * prm[96 + (g4 * 4 + 1) * 2 + c];
        a2 += v.z * prm[96 + (g4 * 4 + 2) * 2 + c];
        a2 += v.w * prm[96 + (g4 * 4 + 3) * 2 + c];
      }
      float lpv = 1.f / (1.f + __expf(-(a2 + lps[tid])));
      p.out[((size_t)(TSEQ - 1) * BATCH + m0 + m) * 2 + c] = lpv;
    }
  }
}

// ---------------------------------------------------------------------------
extern "C" void kernel_launch(void* const* d_in, const int* in_sizes, int n_in,
                              void* d_out, int out_size, void* d_ws, size_t ws_size,
                              hipStream_t stream) {
  char* ws = (char*)d_ws;
  KParams kp;
  kp.last_pos = (const float*)d_in[0];
  kp.hh    = (const float*)d_in[1];
  kp.ch0   = (const float*)d_in[2];
  kp.se_w1 = (const float*)d_in[3];
  kp.se_b1 = (const float*)d_in[4];
  kp.se_g  = (const float*)d_in[5];
  kp.se_bt = (const float*)d_in[6];
  kp.se_m  = (const float*)d_in[7];
  kp.se_v  = (const float*)d_in[8];
  kp.se_w2 = (const float*)d_in[9];
  kp.se_b2 = (const float*)d_in[10];
  kp.w_ih  = (const float*)d_in[11];
  kp.w_hh  = (const float*)d_in[12];
  kp.b_ih  = (const float*)d_in[13];
  kp.b_hh  = (const float*)d_in[14];
  kp.hp_w1 = (const float*)d_in[15];
  kp.hp_b1 = (const float*)d_in[16];
  kp.hp_g  = (const float*)d_in[17];
  kp.hp_bt = (const float*)d_in[18];
  kp.hp_m  = (const float*)d_in[19];
  kp.hp_v  = (const float*)d_in[20];
  kp.hp_w2 = (const float*)d_in[21];
  kp.hp_b2 = (const float*)d_in[22];
  kp.flags = (unsigned*)(ws + WS_FLAGS);
  kp.hatom = ws + WS_HATOM;
  kp.out   = (float*)d_out;

  (void)hipMemsetAsync(ws + WS_FLAGS, 0, 2048, stream);
  (void)hipFuncSetAttribute((const void*)decoder_persist,
                            hipFuncAttributeMaxDynamicSharedMemorySize, LDS_TOTAL);
  decoder_persist<<<dim3(NBLK), dim3(NTHR), LDS_TOTAL, stream>>>(kp);
}